// Round 11
// baseline (327.718 us; speedup 1.0000x reference)
//
#include <hip/hip_runtime.h>
#include <hip/hip_bf16.h>
#include <math.h>

// Dims (fixed by the problem)
#define T_LEN 32
#define BATCH 16
#define DDIM  512
#define HDIM  512
#define EDIM  512
#define CDIM  512
#define FHH   8
#define FWW   32
#define HW    256         // FHH*FWW
#define G4    2048        // 4*HDIM
#define PADH  10
#define PADW  34
#define WLP   520         // padded LDS row stride (ushorts)

typedef __attribute__((ext_vector_type(8))) short bf16x8;
typedef __attribute__((ext_vector_type(4))) float f32x4;
typedef __attribute__((ext_vector_type(4))) int i32x4;

// round-to-nearest-even f32 -> bf16 bits
__device__ __forceinline__ ushort bfr(float x) {
    union { float f; uint32_t u; } c; c.f = x;
    uint32_t r = (c.u + 0x7FFFu + ((c.u >> 16) & 1u)) >> 16;
    return (ushort)r;
}

__device__ __forceinline__ float frcp(float x) { return __builtin_amdgcn_rcpf(x); }
__device__ __forceinline__ float ftanh(float x) {
    return 1.f - 2.f * frcp(1.f + __expf(2.f * x));
}
__device__ __forceinline__ float fsig(float x) {
    return frcp(1.f + __expf(-x));
}

__device__ __forceinline__ void ld_lds16(const void* g, void* l) {
    __builtin_amdgcn_global_load_lds((const __attribute__((address_space(1))) void*)g,
                                     (__attribute__((address_space(3))) void*)l, 16, 0, 0);
}

// ---- sc1 = MALL-coherent (cross-XCD) accesses ----
__device__ __forceinline__ void st_i32_sc1(int* p, int v) {
    asm volatile("global_store_dword %0, %1, off sc1" :: "v"(p), "v"(v) : "memory");
}
__device__ __forceinline__ void st_f32_sc1(float* p, float v) {
    asm volatile("global_store_dword %0, %1, off sc1" :: "v"(p), "v"(v) : "memory");
}
__device__ __forceinline__ void st_i32x4_sc1(int* p, i32x4 v) {
    asm volatile("global_store_dwordx4 %0, %1, off sc1" :: "v"(p), "v"(v) : "memory");
}
__device__ __forceinline__ int ld_i32_sc1(const int* p) {
    int v;
    asm volatile("global_load_dword %0, %1, off sc1\n\ts_waitcnt vmcnt(0)"
                 : "=v"(v) : "v"(p) : "memory");
    return v;
}
__device__ __forceinline__ float ld_f32_sc1(const float* p) {
    float v;
    asm volatile("global_load_dword %0, %1, off sc1\n\ts_waitcnt vmcnt(0)"
                 : "=v"(v) : "v"(p) : "memory");
    return v;
}
// no waitcnt -- caller must vmcnt(0)+sched_barrier before use
__device__ __forceinline__ f32x4 ld_f32x4_sc1_async(const float* p) {
    f32x4 v;
    asm volatile("global_load_dwordx4 %0, %1, off sc1" : "=v"(v) : "v"(p));
    return v;
}
__device__ __forceinline__ i32x4 ld_i32x4_sc1_async(const int* p) {
    i32x4 v;
    asm volatile("global_load_dwordx4 %0, %1, off sc1" : "=v"(v) : "v"(p));
    return v;
}

// ---------------------------------------------------------------------------
// prep_all: one launch for all preprocessing.
//   [0,5120):        f32->bf16 of 7 tensors + zero syncbuf[0..127] (sc1)
//   [5120,7168):     conv_f -> padT interior
//   [7168,7840):     padT border zeros
//   [7840,17056):    W_em -> Wt (9,E,C)
//   [17056,17568):   W_dec -> WdecT bf16
//   [17568,17570):   b_comb[e] = W_hem[e,:]·b_dec + b_hem[e]
//   [17570,18082):   zero hs32 tag buffer (2MB, sc1)
// ---------------------------------------------------------------------------
struct PrepArgs { const float* s[7]; ushort* d[7]; };
__global__ __launch_bounds__(256) void prep_all(
    PrepArgs a, int* __restrict__ syncbuf,
    const float* __restrict__ conv_f, ushort* __restrict__ padT,
    const float* __restrict__ W_em, ushort* __restrict__ Wt,
    const float* __restrict__ W_dec, ushort* __restrict__ WdecT,
    const float* __restrict__ W_hem, const float* __restrict__ b_dec,
    const float* __restrict__ b_hem, float* __restrict__ b_comb,
    int* __restrict__ hs32)
{
    __shared__ float tile[32][33];
    const int bid = blockIdx.x, tid = threadIdx.x;
    if (bid < 5120) {
        int i = bid * 256 + tid;
        if (i < 128) st_i32_sc1(syncbuf + i, 0);
        const int e0 = 65536, e1 = 327680, e2 = 589824, e3 = 851968,
                  e4 = 1114112, e5 = 1245184;
        int seg, base;
        if      (i < e0) { seg = 0; base = 0;  }
        else if (i < e1) { seg = 1; base = e0; }
        else if (i < e2) { seg = 2; base = e1; }
        else if (i < e3) { seg = 3; base = e2; }
        else if (i < e4) { seg = 4; base = e3; }
        else if (i < e5) { seg = 5; base = e4; }
        else             { seg = 6; base = e5; }
        int li = i - base;
        float4 v = ((const float4*)a.s[seg])[li];
        ushort4 o;
        o.x = bfr(v.x); o.y = bfr(v.y); o.z = bfr(v.z); o.w = bfr(v.w);
        ((ushort4*)a.d[seg])[li] = o;
        return;
    }
    if (bid < 7168) {
        int id = bid - 5120;
        int s0 = (id & 7) * 32, c0 = ((id >> 3) & 15) * 32, b = id >> 7;
        int lo = tid & 31, hi = tid >> 5;
#pragma unroll
        for (int it = 0; it < 4; ++it) {
            int cl = hi + it * 8;
            tile[cl][lo] = conv_f[((size_t)(b * CDIM + c0 + cl)) * HW + s0 + lo];
        }
        __syncthreads();
#pragma unroll
        for (int it = 0; it < 4; ++it) {
            int sl = hi + it * 8;
            int s = s0 + sl;
            int y = s >> 5, x = s & 31;
            padT[(((size_t)b * PADH + y + 1) * PADW + (x + 1)) * CDIM + c0 + lo] =
                bfr(tile[lo][sl]);
        }
        return;
    }
    if (bid < 7840) {
        int gid = (bid - 7168) * 256 + tid;
        int c4 = gid & 127;
        int cellb = gid >> 7;
        int cell = cellb % 84;
        int b = cellb / 84;
        int y, x;
        if (cell < 34) { y = 0; x = cell; }
        else if (cell < 68) { y = 9; x = cell - 34; }
        else { int k2 = cell - 68; y = 1 + (k2 >> 1); x = (k2 & 1) ? 33 : 0; }
        ((ushort4*)padT)[(((size_t)b * PADH + y) * PADW + x) * (CDIM / 4) + c4] =
            make_ushort4(0, 0, 0, 0);
        return;
    }
    if (bid < 17056) {
        int gid = (bid - 7840) * 256 + tid;
        int c = gid % CDIM;
        int t = gid / CDIM;
        int e = t % EDIM;
        int tap = t / EDIM;
        int dy = tap / 3, dx = tap % 3;
        Wt[gid] = bfr(W_em[((e * CDIM + c) * 3 + dy) * 3 + dx]);
        return;
    }
    if (bid < 17568) {
        int idx = bid - 17056;
        int ht = idx & 15, kt = idx >> 4;
        int h0 = ht * 32, k0 = kt * 32;
        int lo = tid & 31, hi = tid >> 5;
#pragma unroll
        for (int it = 0; it < 4; ++it) {
            int i = hi + it * 8;
            tile[i][lo] = W_dec[(size_t)(h0 + i) * 1024 + k0 + lo];
        }
        __syncthreads();
#pragma unroll
        for (int it = 0; it < 4; ++it) {
            int i = hi + it * 8;
            WdecT[(size_t)(k0 + i) * 512 + h0 + lo] = bfr(tile[lo][i]);
        }
        return;
    }
    if (bid < 17570) {
        int e = (bid - 17568) * 256 + tid;
        float s = b_hem[e];
        const float* wr = W_hem + (size_t)e * 512;
        for (int h = 0; h < 512; ++h) s += wr[h] * b_dec[h];
        b_comb[e] = s;
        return;
    }
    {
        // zero hs32 (tagged-h exchange buffer) -- MUST happen every call
        int gid = (bid - 17570) * 256 + tid;   // 0..131071 dwordx4
        i32x4 z = {0, 0, 0, 0};
        st_i32x4_sc1(hs32 + (size_t)gid * 4, z);
    }
}

// ---------------------------------------------------------------------------
// shared 64x64 MFMA tile compute: acc += A_tile @ B_tile^T over K.
// ---------------------------------------------------------------------------
__device__ __forceinline__ void tile64_compute(
    const ushort* Ap0, const ushort* Bp0, int K,
    ushort* smem, int tid, f32x4 (&acc)[2][2])
{
    ushort* As = smem;
    ushort* Bs = smem + 2048;
    const int w = tid >> 6, lane = tid & 63;
    ushort* AsW = &As[w * 512];
    ushort* BsW = &Bs[w * 512];
    const int wm = (w >> 1) * 32, wn = (w & 1) * 32;
    const int kb = (lane >> 4) * 8, fr = lane & 15;
    for (int kk = 0; kk < K; kk += 32) {
        __syncthreads();
        ld_lds16(Ap0 + kk, AsW);
        ld_lds16(Bp0 + kk, BsW);
        __syncthreads();
        bf16x8 af[2], bg[2];
#pragma unroll
        for (int i = 0; i < 2; ++i)
            af[i] = *(const bf16x8*)&As[(wm + i * 16 + fr) * 32 + kb];
#pragma unroll
        for (int j = 0; j < 2; ++j)
            bg[j] = *(const bf16x8*)&Bs[(wn + j * 16 + fr) * 32 + kb];
#pragma unroll
        for (int i = 0; i < 2; ++i)
#pragma unroll
            for (int j = 0; j < 2; ++j)
                acc[i][j] = __builtin_amdgcn_mfma_f32_16x16x32_bf16(af[i], bg[j], acc[i][j], 0, 0, 0);
    }
}

// ---------------------------------------------------------------------------
// Fused persistent kernel (bid-ordered roles, round-7 proven dispatch):
//   [0,64):      LSTM. h exchange = TAGGED u32 in hs32 (tag=step+1 in hi16,
//                bf16 h in lo16), sc1 stores; consumers spin on the DATA
//                (no flags, 1 MALL RT). Plain bf16 copy to hs_bf for tail.
//   [64,576):    gx producers -> gxT (sc1) + gcnt.
//   [576,1088):  conv_em 64x64 tiles.
//   [1088,1216): W_comb = W_hem @ W_dec.
// syncbuf: [64..79] gcnt, [96..103] hcnt (tail).
// ---------------------------------------------------------------------------
__global__ __launch_bounds__(256) void fused_main(
    const ushort* __restrict__ Whh_f, const ushort* __restrict__ Whh_b,
    float* __restrict__ gxT_f, float* __restrict__ gxT_b,
    const ushort* __restrict__ hen_bf,
    const ushort* __restrict__ Wih_f, const ushort* __restrict__ Wih_b,
    const float* __restrict__ b_ih_f, const float* __restrict__ b_hh_f,
    const float* __restrict__ b_ih_b, const float* __restrict__ b_hh_b,
    int* __restrict__ hs32, ushort* __restrict__ hs_bf,
    int* __restrict__ syncbuf,
    const ushort* __restrict__ padT, const ushort* __restrict__ Wt,
    const float* __restrict__ bias_em, float* __restrict__ xem,
    const ushort* __restrict__ Whem_bf, const ushort* __restrict__ WdecT_bf,
    ushort* __restrict__ Wcomb_bf)
{
    __shared__ ushort smem[64 * WLP];
    const int bid = blockIdx.x, tid = threadIdx.x;
    const int w = tid >> 6, lane = tid & 63;
    int* gcnt = syncbuf + 64;

    if (bid < 64) {
        // ======================= LSTM (tagged-h exchange) =======================
        const int dir = bid >> 5;
        const int j0 = (bid & 31) * 16;
        const ushort* W = dir ? Whh_b : Whh_f;
        const float* gx = dir ? gxT_b : gxT_f;
#pragma unroll
        for (int i = 0; i < 16; ++i) {
            int row = w * 16 + i;
            int g = row >> 4, jl = row & 15;
            bf16x8 v = *(const bf16x8*)(W + ((size_t)(g * 512 + j0 + jl)) * 512 + lane * 8);
            *(bf16x8*)&smem[row * WLP + lane * 8] = v;
        }
        __syncthreads();
        if (tid >= 64) return;
        __builtin_amdgcn_s_setprio(1);

        const int fr = lane & 15, kq = lane >> 4;
        const int j = j0 + fr;
        // first gx m-tile + step-0 gq prefetch (cross-XCD: sc1)
        const int t0 = dir ? (T_LEN - 1) : 0;
        int mt_ok = t0 >> 2;
        {
            const int* gp = &gcnt[dir * 8 + mt_ok];
            while (ld_i32_sc1(gp) < 32) __builtin_amdgcn_s_sleep(4);
        }
        f32x4 gq[4];
#pragma unroll
        for (int r = 0; r < 4; ++r)
            gq[r] = ld_f32x4_sc1_async(gx + (((size_t)t0 * BATCH + kq * 4 + r) * 512 + j) * 4);
        f32x4 cr = {0.f, 0.f, 0.f, 0.f};
        for (int step = 0; step < T_LEN; ++step) {
            const int tcur = dir ? (T_LEN - 1 - step) : step;
            f32x4 acc[4];
#pragma unroll
            for (int g = 0; g < 4; ++g) acc[g] = {0.f, 0.f, 0.f, 0.f};
            if (step > 0) {
                const int tprev = dir ? tcur + 1 : tcur - 1;
                const uint taghi = (uint)step;   // producer wrote tag = step
                const int* hb = hs32 + ((size_t)tprev * BATCH + fr) * 1024 + dir * 512 + kq * 8;
                // two halves of 8 K-chunks; spin on the data itself
#pragma unroll
                for (int H = 0; H < 2; ++H) {
                    const int* hbH = hb + H * 256;
                    i32x4 L[16];
                    for (;;) {
#pragma unroll
                        for (int c = 0; c < 8; ++c) {
                            L[2 * c]     = ld_i32x4_sc1_async(hbH + c * 32);
                            L[2 * c + 1] = ld_i32x4_sc1_async(hbH + c * 32 + 4);
                        }
                        asm volatile("s_waitcnt vmcnt(0)" ::: "memory");
                        __builtin_amdgcn_sched_barrier(0);
                        uint err = 0;
#pragma unroll
                        for (int q = 0; q < 16; ++q)
#pragma unroll
                            for (int z = 0; z < 4; ++z)
                                err |= ((uint)L[q][z] >> 16) ^ taghi;
                        if (__all(err == 0)) break;
                        __builtin_amdgcn_s_sleep(1);
                    }
                    // pack low halves -> bf16x8 fragments, MFMA
#pragma unroll
                    for (int c = 0; c < 8; ++c) {
                        union { bf16x8 v; uint u[4]; } ua;
                        uint e0 = (uint)L[2 * c][0], e1 = (uint)L[2 * c][1];
                        uint e2 = (uint)L[2 * c][2], e3 = (uint)L[2 * c][3];
                        uint e4 = (uint)L[2 * c + 1][0], e5 = (uint)L[2 * c + 1][1];
                        uint e6 = (uint)L[2 * c + 1][2], e7 = (uint)L[2 * c + 1][3];
                        ua.u[0] = (e1 << 16) | (e0 & 0xFFFFu);
                        ua.u[1] = (e3 << 16) | (e2 & 0xFFFFu);
                        ua.u[2] = (e5 << 16) | (e4 & 0xFFFFu);
                        ua.u[3] = (e7 << 16) | (e6 & 0xFFFFu);
                        const int kk = H * 256 + c * 32;
#pragma unroll
                        for (int g = 0; g < 4; ++g) {
                            bf16x8 bb = *(const bf16x8*)&smem[(g * 16 + fr) * WLP + kq * 8 + kk];
                            acc[g] = __builtin_amdgcn_mfma_f32_16x16x32_bf16(ua.v, bb, acc[g], 0, 0, 0);
                        }
                    }
                }
            } else {
                asm volatile("s_waitcnt vmcnt(0)" ::: "memory");  // gq arrival
                __builtin_amdgcn_sched_barrier(0);
            }
            // epilogue: batch = kq*4+r, col j; tagged sc1 + plain bf16 stores
            const uint tw = (uint)(step + 1) << 16;
#pragma unroll
            for (int r = 0; r < 4; ++r) {
                int b = kq * 4 + r;
                float gi = gq[r][0] + acc[0][r];
                float gf = gq[r][1] + acc[1][r];
                float gg = gq[r][2] + acc[2][r];
                float go = gq[r][3] + acc[3][r];
                float si = fsig(gi), sf = fsig(gf), so = fsig(go);
                float c = sf * cr[r] + si * ftanh(gg);
                cr[r] = c;
                float h = so * ftanh(c);
                ushort hb16 = bfr(h);
                size_t idx = ((size_t)tcur * BATCH + b) * 1024 + dir * 512 + j;
                st_i32_sc1(hs32 + idx, (int)(tw | (uint)hb16));
                hs_bf[idx] = hb16;            // plain: consumed by tail kernel
            }
            if (step < T_LEN - 1) {
                // prefetch next step's gq (latency hides under next data-spin)
                const int tnext = dir ? tcur - 1 : tcur + 1;
                const int mtn = tnext >> 2;
                if (mtn != mt_ok) {
                    const int* gp = &gcnt[dir * 8 + mtn];
                    while (ld_i32_sc1(gp) < 32) __builtin_amdgcn_s_sleep(2);
                    mt_ok = mtn;
                }
#pragma unroll
                for (int r = 0; r < 4; ++r)
                    gq[r] = ld_f32x4_sc1_async(gx + (((size_t)tnext * BATCH + kq * 4 + r) * 512 + j) * 4);
            }
        }
        return;
    }

    // ======================= workers =======================
    const int r0 = tid >> 2, c0 = (tid & 3) * 8;
    const int wm = (w >> 1) * 32, wn = (w & 1) * 32;
    const int col = lane & 15, rq = (lane >> 4) * 4;
    f32x4 acc[2][2];
#pragma unroll
    for (int i = 0; i < 2; ++i)
#pragma unroll
        for (int j = 0; j < 2; ++j) acc[i][j] = {0.f, 0.f, 0.f, 0.f};

    if (bid < 576) {
        // ---- gx producers ----
        const int gi = bid - 64;
        const int dir = gi & 1;
        const int q = gi >> 1;
        const int nt = q & 31;
        const int mt0 = q >> 5;
        const int mtile = dir ? (7 - mt0) : mt0;
        const ushort* Bw = dir ? Wih_b : Wih_f;
        const float* bi0 = dir ? b_ih_b : b_ih_f;
        const float* bi1 = dir ? b_hh_b : b_hh_f;
        float* Cg = dir ? gxT_b : gxT_f;
        const int m0 = mtile * 64, n0 = nt * 64;
        tile64_compute(hen_bf + (size_t)(m0 + r0) * 512 + c0,
                       Bw + (size_t)(n0 + r0) * 512 + c0, 512, smem, tid, acc);
#pragma unroll
        for (int i = 0; i < 2; ++i)
#pragma unroll
            for (int r = 0; r < 4; ++r) {
                int m = m0 + wm + i * 16 + rq + r;
#pragma unroll
                for (int j2 = 0; j2 < 2; ++j2) {
                    int n = n0 + wn + j2 * 16 + col;
                    st_f32_sc1(&Cg[(size_t)m * G4 + (n & 511) * 4 + (n >> 9)],
                               acc[i][j2][r] + bi0[n] + bi1[n]);
                }
            }
        asm volatile("s_waitcnt vmcnt(0)" ::: "memory");
        __syncthreads();
        if (tid == 0) atomicAdd(&gcnt[dir * 8 + mtile], 1);
        return;
    }
    if (bid < 1088) {
        // ---- conv ----
        const int cbid = bid - 576;
        const int n0 = (cbid & 7) * 64, m0 = (cbid >> 3) * 64;
        const int b = m0 >> 8, s0 = m0 & 255, y0 = s0 >> 5;
        const int y = y0 + (r0 >> 5), x = r0 & 31;
        const ushort* Abase = padT + (((size_t)b * PADH + y) * PADW + x) * CDIM + c0;
        const ushort* Bbase = Wt + (size_t)(n0 + r0) * CDIM + c0;
        for (int tap = 0; tap < 9; ++tap) {
            const int dy = tap / 3, dx = tap % 3;
            tile64_compute(Abase + ((size_t)dy * PADW + dx) * CDIM,
                           Bbase + (size_t)tap * EDIM * CDIM, 512, smem, tid, acc);
        }
#pragma unroll
        for (int i = 0; i < 2; ++i)
#pragma unroll
            for (int r = 0; r < 4; ++r) {
                int m = m0 + wm + i * 16 + rq + r;
                int s = m & 255;
#pragma unroll
                for (int j2 = 0; j2 < 2; ++j2) {
                    int e = n0 + wn + j2 * 16 + col;
                    xem[((size_t)b * EDIM + e) * HW + s] = acc[i][j2][r] + bias_em[e];
                }
            }
        return;
    }
    {
        // ---- W_comb = W_hem @ W_dec ----
        const int wb = bid - 1088;
        const int mt = wb >> 4, nt = wb & 15;
        const int m0 = mt * 64, n0 = nt * 64;
        tile64_compute(Whem_bf + (size_t)(m0 + r0) * 512 + c0,
                       WdecT_bf + (size_t)(n0 + r0) * 512 + c0, 512, smem, tid, acc);
#pragma unroll
        for (int i = 0; i < 2; ++i)
#pragma unroll
            for (int r = 0; r < 4; ++r) {
                int m = m0 + wm + i * 16 + rq + r;
#pragma unroll
                for (int j2 = 0; j2 < 2; ++j2) {
                    int n = n0 + wn + j2 * 16 + col;
                    Wcomb_bf[(size_t)m * 1024 + n] = bfr(acc[i][j2][r]);
                }
            }
    }
}

// ---------------------------------------------------------------------------
// tail: decode (64 blocks -> out[:, :, 0:512]) || h_em (64 blocks, W_comb,
// sc1 + hcnt) || attention (512 blocks, waits on hcnt).
// ---------------------------------------------------------------------------
__global__ __launch_bounds__(256) void tail(
    const ushort* __restrict__ hs_bf, const ushort* __restrict__ Wdec_bf,
    const float* __restrict__ b_dec, float* __restrict__ out,
    const ushort* __restrict__ Wcomb_bf, const float* __restrict__ b_comb,
    float* __restrict__ h_em,
    const float* __restrict__ xem, const float* __restrict__ watt,
    int* __restrict__ syncbuf)
{
    __shared__ ushort smem[4096];
    int* hcnt = syncbuf + 96;
    const int bid = blockIdx.x, tid = threadIdx.x;
    const int w = tid >> 6, lane = tid & 63;
    const int r0 = tid >> 2, c0 = (tid & 3) * 8;
    const int wm = (w >> 1) * 32, wn = (w & 1) * 32;
    const int col = lane & 15, rq = (lane >> 4) * 4;

    if (bid < 128) {
        f32x4 acc[2][2];
#pragma unroll
        for (int i = 0; i < 2; ++i)
#pragma unroll
            for (int j = 0; j < 2; ++j) acc[i][j] = {0.f, 0.f, 0.f, 0.f};
        if (bid < 64) {
            const int mt = bid >> 3, nt = bid & 7;
            const int m0 = mt * 64, n0 = nt * 64;
            tile64_compute(hs_bf + (size_t)(m0 + r0) * 1024 + c0,
                           Wdec_bf + (size_t)(n0 + r0) * 1024 + c0, 1024, smem, tid, acc);
#pragma unroll
            for (int i = 0; i < 2; ++i)
#pragma unroll
                for (int r = 0; r < 4; ++r) {
                    int m = m0 + wm + i * 16 + rq + r;
                    int t = m >> 4, b = m & 15;
#pragma unroll
                    for (int j2 = 0; j2 < 2; ++j2) {
                        int n = n0 + wn + j2 * 16 + col;
                        out[((size_t)(b * T_LEN + t)) * 1024 + n] = acc[i][j2][r] + b_dec[n];
                    }
                }
        } else {
            const int blk = bid - 64;
            const int mt = blk >> 3, nt = blk & 7;
            const int m0 = mt * 64, n0 = nt * 64;
            tile64_compute(hs_bf + (size_t)(m0 + r0) * 1024 + c0,
                           Wcomb_bf + (size_t)(n0 + r0) * 1024 + c0, 1024, smem, tid, acc);
#pragma unroll
            for (int i = 0; i < 2; ++i)
#pragma unroll
                for (int r = 0; r < 4; ++r) {
                    int m = m0 + wm + i * 16 + rq + r;
#pragma unroll
                    for (int j2 = 0; j2 < 2; ++j2) {
                        int n = n0 + wn + j2 * 16 + col;
                        st_f32_sc1(&h_em[(size_t)m * 512 + n], acc[i][j2][r] + b_comb[n]);
                    }
                }
            asm volatile("s_waitcnt vmcnt(0)" ::: "memory");
            __syncthreads();
            if (tid == 0) atomicAdd(&hcnt[mt], 1);
        }
        return;
    }

    // ---- attention ----
    {
        int i = bid - 128;
        int k = i >> 3;
        int b = ((i & 7) << 1) | (k & 1);
        int t = k >> 1;
        int tb = t * 16 + b;
        const int mt = tb >> 6;
        if (tid == 0) {
            while (ld_i32_sc1(&hcnt[mt]) < 8) __builtin_amdgcn_s_sleep(8);
        }
        __syncthreads();
        float* fs = (float*)smem;
        float* hl = fs;
        float* wl = fs + 512;
        float* al = fs + 1024;
        float* red = fs + 1280;
        for (int q = tid; q < 512; q += 256) {
            hl[q] = ld_f32_sc1(&h_em[(size_t)tb * 512 + q]);
            wl[q] = watt[q];
        }
        __syncthreads();
        const float* xb = xem + (size_t)b * EDIM * HW;
        float sc = 0.f;
#pragma unroll 4
        for (int e = 0; e < 512; ++e)
            sc += ftanh(xb[(size_t)e * HW + tid] + hl[e]) * wl[e];
        float m = sc;
#pragma unroll
        for (int o = 32; o; o >>= 1) m = fmaxf(m, __shfl_xor(m, o));
        if ((tid & 63) == 0) red[tid >> 6] = m;
        __syncthreads();
        m = fmaxf(fmaxf(red[0], red[1]), fmaxf(red[2], red[3]));
        float ex = __expf(sc - m);
        float s = ex;
#pragma unroll
        for (int o = 32; o; o >>= 1) s += __shfl_xor(s, o);
        if ((tid & 63) == 0) red[4 + (tid >> 6)] = s;
        __syncthreads();
        s = red[4] + red[5] + red[6] + red[7];
        al[tid] = ex * frcp(s);
        __syncthreads();
        float* ob = out + ((size_t)(b * T_LEN + t)) * 1024 + 512;
        for (int eo = 0; eo < 512; eo += 256) {
            int e = eo + tid;
            const float* xr = xb + (size_t)e * HW;
            float acc2 = 0.f;
#pragma unroll 4
            for (int n = 0; n < 256; n += 4) {
                float4 v = *(const float4*)&xr[n];
                acc2 += al[n] * v.x + al[n + 1] * v.y + al[n + 2] * v.z + al[n + 3] * v.w;
            }
            ob[e] = acc2;
        }
    }
}

// ---------------------------------------------------------------------------
extern "C" void kernel_launch(void* const* d_in, const int* in_sizes, int n_in,
                              void* d_out, int out_size, void* d_ws, size_t ws_size,
                              hipStream_t stream) {
    const float* hidden_en = (const float*)d_in[0];
    const float* conv_f    = (const float*)d_in[1];
    const float* W_ih_f    = (const float*)d_in[2];
    const float* W_hh_f    = (const float*)d_in[3];
    const float* b_ih_f    = (const float*)d_in[4];
    const float* b_hh_f    = (const float*)d_in[5];
    const float* W_ih_b    = (const float*)d_in[6];
    const float* W_hh_b    = (const float*)d_in[7];
    const float* b_ih_b    = (const float*)d_in[8];
    const float* b_hh_b    = (const float*)d_in[9];
    const float* W_dec     = (const float*)d_in[10];
    const float* b_dec     = (const float*)d_in[11];
    const float* W_em      = (const float*)d_in[12];
    const float* b_em      = (const float*)d_in[13];
    const float* W_hem     = (const float*)d_in[14];
    const float* b_hem     = (const float*)d_in[15];
    const float* w_att     = (const float*)d_in[16];
    float* out = (float*)d_out;

    char* p = (char*)d_ws;
    auto alloc = [&](size_t bytes) { void* r = p; p += (bytes + 255) & ~(size_t)255; return r; };
    float*    gxT_f   = (float*)alloc((size_t)T_LEN * BATCH * G4 * 4);
    float*    gxT_b   = (float*)alloc((size_t)T_LEN * BATCH * G4 * 4);
    float*    h_em    = (float*)alloc((size_t)T_LEN * BATCH * 512 * 4);
    float*    x_em    = (float*)alloc((size_t)BATCH * EDIM * HW * 4);
    ushort*   padT    = (ushort*)alloc((size_t)BATCH * PADH * PADW * CDIM * 2);
    ushort*   Wt      = (ushort*)alloc((size_t)9 * EDIM * CDIM * 2);
    ushort*   hen_bf  = (ushort*)alloc((size_t)T_LEN * BATCH * DDIM * 2);
    ushort*   Wihf_bf = (ushort*)alloc((size_t)G4 * DDIM * 2);
    ushort*   Wihb_bf = (ushort*)alloc((size_t)G4 * DDIM * 2);
    ushort*   Whhf_bf = (ushort*)alloc((size_t)G4 * HDIM * 2);
    ushort*   Whhb_bf = (ushort*)alloc((size_t)G4 * HDIM * 2);
    ushort*   Wdec_bf = (ushort*)alloc((size_t)HDIM * 1024 * 2);
    ushort*   Whem_bf = (ushort*)alloc((size_t)EDIM * HDIM * 2);
    ushort*   WdecT_bf= (ushort*)alloc((size_t)1024 * 512 * 2);
    ushort*   Wcomb_bf= (ushort*)alloc((size_t)512 * 1024 * 2);
    float*    b_comb  = (float*)alloc(512 * 4);
    int*      hs32    = (int*)alloc((size_t)T_LEN * BATCH * 1024 * 4);  // tagged h
    ushort*   hs_bf   = (ushort*)alloc((size_t)T_LEN * BATCH * 1024 * 2);
    int*      syncbuf = (int*)alloc(1024);

    PrepArgs pa;
    pa.s[0] = hidden_en; pa.d[0] = hen_bf;
    pa.s[1] = W_ih_f;    pa.d[1] = Wihf_bf;
    pa.s[2] = W_ih_b;    pa.d[2] = Wihb_bf;
    pa.s[3] = W_hh_f;    pa.d[3] = Whhf_bf;
    pa.s[4] = W_hh_b;    pa.d[4] = Whhb_bf;
    pa.s[5] = W_dec;     pa.d[5] = Wdec_bf;
    pa.s[6] = W_hem;     pa.d[6] = Whem_bf;
    prep_all<<<18082, 256, 0, stream>>>(pa, syncbuf, conv_f, padT, W_em, Wt,
                                        W_dec, WdecT_bf, W_hem, b_dec, b_hem,
                                        b_comb, hs32);

    // LSTM (tagged-h exchange) + gx + conv + W_comb, one persistent launch
    fused_main<<<1216, 256, 0, stream>>>(Whhf_bf, Whhb_bf, gxT_f, gxT_b, hen_bf,
                                         Wihf_bf, Wihb_bf, b_ih_f, b_hh_f,
                                         b_ih_b, b_hh_b, hs32, hs_bf, syncbuf,
                                         padT, Wt, b_em, x_em,
                                         Whem_bf, WdecT_bf, Wcomb_bf);

    // decode || h_em || attention
    tail<<<640, 256, 0, stream>>>(hs_bf, Wdec_bf, b_dec, out,
                                  Wcomb_bf, b_comb, h_em, x_em, w_att, syncbuf);
}

// Round 12
// 281.043 us; speedup vs baseline: 1.1661x; 1.1661x over previous
//
#include <hip/hip_runtime.h>
#include <hip/hip_bf16.h>
#include <math.h>

// Dims (fixed by the problem)
#define T_LEN 32
#define BATCH 16
#define DDIM  512
#define HDIM  512
#define EDIM  512
#define CDIM  512
#define FHH   8
#define FWW   32
#define HW    256         // FHH*FWW
#define G4    2048        // 4*HDIM
#define PADH  10
#define PADW  34
#define WLP   520         // padded LDS row stride (ushorts)

typedef __attribute__((ext_vector_type(8))) short bf16x8;
typedef __attribute__((ext_vector_type(4))) float f32x4;
typedef __attribute__((ext_vector_type(4))) int i32x4;

// round-to-nearest-even f32 -> bf16 bits
__device__ __forceinline__ ushort bfr(float x) {
    union { float f; uint32_t u; } c; c.f = x;
    uint32_t r = (c.u + 0x7FFFu + ((c.u >> 16) & 1u)) >> 16;
    return (ushort)r;
}

__device__ __forceinline__ float frcp(float x) { return __builtin_amdgcn_rcpf(x); }
__device__ __forceinline__ float ftanh(float x) {
    return 1.f - 2.f * frcp(1.f + __expf(2.f * x));
}
__device__ __forceinline__ float fsig(float x) {
    return frcp(1.f + __expf(-x));
}

__device__ __forceinline__ void ld_lds16(const void* g, void* l) {
    __builtin_amdgcn_global_load_lds((const __attribute__((address_space(1))) void*)g,
                                     (__attribute__((address_space(3))) void*)l, 16, 0, 0);
}

// ---- sc1 = MALL-coherent (cross-XCD) accesses ----
__device__ __forceinline__ void st_u16_sc1(ushort* p, ushort v) {
    asm volatile("global_store_short %0, %1, off sc1" :: "v"(p), "v"((uint)v) : "memory");
}
__device__ __forceinline__ void st_i32_sc1(int* p, int v) {
    asm volatile("global_store_dword %0, %1, off sc1" :: "v"(p), "v"(v) : "memory");
}
__device__ __forceinline__ void st_f32_sc1(float* p, float v) {
    asm volatile("global_store_dword %0, %1, off sc1" :: "v"(p), "v"(v) : "memory");
}
__device__ __forceinline__ int ld_i32_sc1(const int* p) {
    int v;
    asm volatile("global_load_dword %0, %1, off sc1\n\ts_waitcnt vmcnt(0)"
                 : "=v"(v) : "v"(p) : "memory");
    return v;
}
__device__ __forceinline__ i32x4 ld_i32x4_sc1(const int* p) {
    i32x4 v;
    asm volatile("global_load_dwordx4 %0, %1, off sc1\n\ts_waitcnt vmcnt(0)"
                 : "=v"(v) : "v"(p) : "memory");
    return v;
}
__device__ __forceinline__ float ld_f32_sc1(const float* p) {
    float v;
    asm volatile("global_load_dword %0, %1, off sc1\n\ts_waitcnt vmcnt(0)"
                 : "=v"(v) : "v"(p) : "memory");
    return v;
}
// no waitcnt -- caller must vmcnt(0)+sched_barrier before use
__device__ __forceinline__ f32x4 ld_f32x4_sc1_async(const float* p) {
    f32x4 v;
    asm volatile("global_load_dwordx4 %0, %1, off sc1" : "=v"(v) : "v"(p));
    return v;
}

// ---------------------------------------------------------------------------
// prep_all: one launch for all preprocessing.
//   [0,5120):        f32->bf16 of 7 tensors + zero syncbuf[0..127] (sc1)
//   [5120,7168):     conv_f -> padT interior
//   [7168,7840):     padT border zeros
//   [7840,17056):    W_em -> Wt (9,E,C)
//   [17056,17568):   W_dec -> WdecT bf16
//   [17568,17570):   b_comb[e] = W_hem[e,:]·b_dec + b_hem[e]
// ---------------------------------------------------------------------------
struct PrepArgs { const float* s[7]; ushort* d[7]; };
__global__ __launch_bounds__(256) void prep_all(
    PrepArgs a, int* __restrict__ syncbuf,
    const float* __restrict__ conv_f, ushort* __restrict__ padT,
    const float* __restrict__ W_em, ushort* __restrict__ Wt,
    const float* __restrict__ W_dec, ushort* __restrict__ WdecT,
    const float* __restrict__ W_hem, const float* __restrict__ b_dec,
    const float* __restrict__ b_hem, float* __restrict__ b_comb)
{
    __shared__ float tile[32][33];
    const int bid = blockIdx.x, tid = threadIdx.x;
    if (bid < 5120) {
        int i = bid * 256 + tid;
        if (i < 128) st_i32_sc1(syncbuf + i, 0);
        const int e0 = 65536, e1 = 327680, e2 = 589824, e3 = 851968,
                  e4 = 1114112, e5 = 1245184;
        int seg, base;
        if      (i < e0) { seg = 0; base = 0;  }
        else if (i < e1) { seg = 1; base = e0; }
        else if (i < e2) { seg = 2; base = e1; }
        else if (i < e3) { seg = 3; base = e2; }
        else if (i < e4) { seg = 4; base = e3; }
        else if (i < e5) { seg = 5; base = e4; }
        else             { seg = 6; base = e5; }
        int li = i - base;
        float4 v = ((const float4*)a.s[seg])[li];
        ushort4 o;
        o.x = bfr(v.x); o.y = bfr(v.y); o.z = bfr(v.z); o.w = bfr(v.w);
        ((ushort4*)a.d[seg])[li] = o;
        return;
    }
    if (bid < 7168) {
        int id = bid - 5120;
        int s0 = (id & 7) * 32, c0 = ((id >> 3) & 15) * 32, b = id >> 7;
        int lo = tid & 31, hi = tid >> 5;
#pragma unroll
        for (int it = 0; it < 4; ++it) {
            int cl = hi + it * 8;
            tile[cl][lo] = conv_f[((size_t)(b * CDIM + c0 + cl)) * HW + s0 + lo];
        }
        __syncthreads();
#pragma unroll
        for (int it = 0; it < 4; ++it) {
            int sl = hi + it * 8;
            int s = s0 + sl;
            int y = s >> 5, x = s & 31;
            padT[(((size_t)b * PADH + y + 1) * PADW + (x + 1)) * CDIM + c0 + lo] =
                bfr(tile[lo][sl]);
        }
        return;
    }
    if (bid < 7840) {
        int gid = (bid - 7168) * 256 + tid;
        int c4 = gid & 127;
        int cellb = gid >> 7;
        int cell = cellb % 84;
        int b = cellb / 84;
        int y, x;
        if (cell < 34) { y = 0; x = cell; }
        else if (cell < 68) { y = 9; x = cell - 34; }
        else { int k2 = cell - 68; y = 1 + (k2 >> 1); x = (k2 & 1) ? 33 : 0; }
        ((ushort4*)padT)[(((size_t)b * PADH + y) * PADW + x) * (CDIM / 4) + c4] =
            make_ushort4(0, 0, 0, 0);
        return;
    }
    if (bid < 17056) {
        int gid = (bid - 7840) * 256 + tid;
        int c = gid % CDIM;
        int t = gid / CDIM;
        int e = t % EDIM;
        int tap = t / EDIM;
        int dy = tap / 3, dx = tap % 3;
        Wt[gid] = bfr(W_em[((e * CDIM + c) * 3 + dy) * 3 + dx]);
        return;
    }
    if (bid < 17568) {
        int idx = bid - 17056;
        int ht = idx & 15, kt = idx >> 4;
        int h0 = ht * 32, k0 = kt * 32;
        int lo = tid & 31, hi = tid >> 5;
#pragma unroll
        for (int it = 0; it < 4; ++it) {
            int i = hi + it * 8;
            tile[i][lo] = W_dec[(size_t)(h0 + i) * 1024 + k0 + lo];
        }
        __syncthreads();
#pragma unroll
        for (int it = 0; it < 4; ++it) {
            int i = hi + it * 8;
            WdecT[(size_t)(k0 + i) * 512 + h0 + lo] = bfr(tile[lo][i]);
        }
        return;
    }
    {
        int e = (bid - 17568) * 256 + tid;
        float s = b_hem[e];
        const float* wr = W_hem + (size_t)e * 512;
        for (int h = 0; h < 512; ++h) s += wr[h] * b_dec[h];
        b_comb[e] = s;
    }
}

// ---------------------------------------------------------------------------
// shared 64x64 MFMA tile compute: acc += A_tile @ B_tile^T over K.
// ---------------------------------------------------------------------------
__device__ __forceinline__ void tile64_compute(
    const ushort* Ap0, const ushort* Bp0, int K,
    ushort* smem, int tid, f32x4 (&acc)[2][2])
{
    ushort* As = smem;
    ushort* Bs = smem + 2048;
    const int w = tid >> 6, lane = tid & 63;
    ushort* AsW = &As[w * 512];
    ushort* BsW = &Bs[w * 512];
    const int wm = (w >> 1) * 32, wn = (w & 1) * 32;
    const int kb = (lane >> 4) * 8, fr = lane & 15;
    for (int kk = 0; kk < K; kk += 32) {
        __syncthreads();
        ld_lds16(Ap0 + kk, AsW);
        ld_lds16(Bp0 + kk, BsW);
        __syncthreads();
        bf16x8 af[2], bg[2];
#pragma unroll
        for (int i = 0; i < 2; ++i)
            af[i] = *(const bf16x8*)&As[(wm + i * 16 + fr) * 32 + kb];
#pragma unroll
        for (int j = 0; j < 2; ++j)
            bg[j] = *(const bf16x8*)&Bs[(wn + j * 16 + fr) * 32 + kb];
#pragma unroll
        for (int i = 0; i < 2; ++i)
#pragma unroll
            for (int j = 0; j < 2; ++j)
                acc[i][j] = __builtin_amdgcn_mfma_f32_16x16x32_bf16(af[i], bg[j], acc[i][j], 0, 0, 0);
    }
}

// ---------------------------------------------------------------------------
// fused_all: everything after prep in ONE persistent kernel (bid-ordered
// roles; every spinner is later in bid order than all its producers):
//   [0,64):      LSTM (round-7 flag exchange, sc1; flag also at final step).
//   [64,576):    gx producers -> gxT (sc1) + gcnt.
//   [576,1088):  conv -> x_em (sc1) + ccnt.
//   [1088,1216): W_comb = W_hem @ W_dec (sc1) + wcnt.
//   [1216,1280): decode (waits per-tile LSTM flags) -> out[:, :, 0:512].
//   [1280,1344): h_em (waits flags + wcnt) -> h_em (sc1) + hcnt.
//   [1344,1856): attention (waits hcnt + ccnt) -> out[:, :, 512:].
// syncbuf: [0..63] step flags, [64..79] gcnt, [96..103] hcnt, [104] ccnt,
//          [105] wcnt. All zeroed by prep (sc1).
// ---------------------------------------------------------------------------
__global__ __launch_bounds__(256) void fused_all(
    const ushort* __restrict__ Whh_f, const ushort* __restrict__ Whh_b,
    float* __restrict__ gxT_f, float* __restrict__ gxT_b,
    const ushort* __restrict__ hen_bf,
    const ushort* __restrict__ Wih_f, const ushort* __restrict__ Wih_b,
    const float* __restrict__ b_ih_f, const float* __restrict__ b_hh_f,
    const float* __restrict__ b_ih_b, const float* __restrict__ b_hh_b,
    ushort* __restrict__ hs_bf,
    int* __restrict__ syncbuf,
    const ushort* __restrict__ padT, const ushort* __restrict__ Wt,
    const float* __restrict__ bias_em, float* __restrict__ xem,
    const ushort* __restrict__ Whem_bf, const ushort* __restrict__ WdecT_bf,
    ushort* __restrict__ Wcomb_bf,
    const ushort* __restrict__ Wdec_bf, const float* __restrict__ b_dec,
    const float* __restrict__ b_comb, float* __restrict__ h_em,
    const float* __restrict__ watt, float* __restrict__ out)
{
    __shared__ ushort smem[64 * WLP];
    const int bid = blockIdx.x, tid = threadIdx.x;
    const int w = tid >> 6, lane = tid & 63;
    int* flags = syncbuf;
    int* gcnt  = syncbuf + 64;
    int* hcnt  = syncbuf + 96;
    int* ccnt  = syncbuf + 104;
    int* wcnt  = syncbuf + 105;

    if (bid < 64) {
        // ======================= LSTM =======================
        const int dir = bid >> 5;
        const int j0 = (bid & 31) * 16;
        const ushort* W = dir ? Whh_b : Whh_f;
        const float* gx = dir ? gxT_b : gxT_f;
#pragma unroll
        for (int i = 0; i < 16; ++i) {
            int row = w * 16 + i;
            int g = row >> 4, jl = row & 15;
            bf16x8 v = *(const bf16x8*)(W + ((size_t)(g * 512 + j0 + jl)) * 512 + lane * 8);
            *(bf16x8*)&smem[row * WLP + lane * 8] = v;
        }
        __syncthreads();
        if (tid >= 64) return;
        __builtin_amdgcn_s_setprio(1);

        const int fr = lane & 15, kq = lane >> 4;
        const int j = j0 + fr;
        const int* fq4 = &flags[dir * 32 + (lane & 7) * 4];
        const int t0 = dir ? (T_LEN - 1) : 0;
        int mt_ok = t0 >> 2;
        {
            const int* gp = &gcnt[dir * 8 + mt_ok];
            while (ld_i32_sc1(gp) < 32) __builtin_amdgcn_s_sleep(4);
        }
        f32x4 gq[4];
#pragma unroll
        for (int r = 0; r < 4; ++r)
            gq[r] = ld_f32x4_sc1_async(gx + (((size_t)t0 * BATCH + kq * 4 + r) * 512 + j) * 4);
        f32x4 cr = {0.f, 0.f, 0.f, 0.f};
        for (int step = 0; step < T_LEN; ++step) {
            const int tcur = dir ? (T_LEN - 1 - step) : step;
            if (step > 0) {
                const int need = step;
                for (;;) {
                    i32x4 v = ld_i32x4_sc1(fq4);
                    int mn = min(min(v[0], v[1]), min(v[2], v[3]));
                    if (__all(mn >= need)) break;
                    __builtin_amdgcn_s_sleep(1);
                }
            }
            f32x4 acc[4];
#pragma unroll
            for (int g = 0; g < 4; ++g) acc[g] = {0.f, 0.f, 0.f, 0.f};
            if (step > 0) {
                const int tprev = dir ? tcur + 1 : tcur - 1;
                const ushort* hp = hs_bf + ((size_t)tprev * BATCH + fr) * 1024 + dir * 512 + kq * 8;
                bf16x8 hreg[16];
#pragma unroll
                for (int u = 0; u < 16; ++u)
                    asm volatile("global_load_dwordx4 %0, %1, off sc1"
                                 : "=v"(hreg[u]) : "v"(hp + u * 32));
                asm volatile("s_waitcnt vmcnt(0)" ::: "memory");
                __builtin_amdgcn_sched_barrier(0);
#pragma unroll
                for (int u = 0; u < 16; ++u) {
#pragma unroll
                    for (int g = 0; g < 4; ++g) {
                        bf16x8 bb = *(const bf16x8*)&smem[(g * 16 + fr) * WLP + kq * 8 + u * 32];
                        acc[g] = __builtin_amdgcn_mfma_f32_16x16x32_bf16(hreg[u], bb, acc[g], 0, 0, 0);
                    }
                }
            } else {
                asm volatile("s_waitcnt vmcnt(0)" ::: "memory");  // gq arrival
                __builtin_amdgcn_sched_barrier(0);
            }
#pragma unroll
            for (int r = 0; r < 4; ++r) {
                int b = kq * 4 + r;
                float gi = gq[r][0] + acc[0][r];
                float gf = gq[r][1] + acc[1][r];
                float gg = gq[r][2] + acc[2][r];
                float go = gq[r][3] + acc[3][r];
                float si = fsig(gi), sf = fsig(gf), so = fsig(go);
                float c = sf * cr[r] + si * ftanh(gg);
                cr[r] = c;
                float h = so * ftanh(c);
                st_u16_sc1(hs_bf + ((size_t)tcur * BATCH + b) * 1024 + dir * 512 + j, bfr(h));
            }
            // h committed, then step flag (every step incl. last: gates tail roles)
            asm volatile("s_waitcnt vmcnt(0)" ::: "memory");
            if (lane == 0) st_i32_sc1(&flags[bid], step + 1);
            if (step < T_LEN - 1) {
                const int tnext = dir ? tcur - 1 : tcur + 1;
                const int mtn = tnext >> 2;
                if (mtn != mt_ok) {
                    const int* gp = &gcnt[dir * 8 + mtn];
                    while (ld_i32_sc1(gp) < 32) __builtin_amdgcn_s_sleep(2);
                    mt_ok = mtn;
                }
#pragma unroll
                for (int r = 0; r < 4; ++r)
                    gq[r] = ld_f32x4_sc1_async(gx + (((size_t)tnext * BATCH + kq * 4 + r) * 512 + j) * 4);
            }
        }
        return;
    }

    const int r0 = tid >> 2, c0 = (tid & 3) * 8;
    const int wm = (w >> 1) * 32, wn = (w & 1) * 32;
    const int col = lane & 15, rq = (lane >> 4) * 4;

    if (bid < 1216) {
        f32x4 acc[2][2];
#pragma unroll
        for (int i = 0; i < 2; ++i)
#pragma unroll
            for (int j = 0; j < 2; ++j) acc[i][j] = {0.f, 0.f, 0.f, 0.f};

        if (bid < 576) {
            // ---- gx producers ----
            const int gi = bid - 64;
            const int dir = gi & 1;
            const int q = gi >> 1;
            const int nt = q & 31;
            const int mt0 = q >> 5;
            const int mtile = dir ? (7 - mt0) : mt0;
            const ushort* Bw = dir ? Wih_b : Wih_f;
            const float* bi0 = dir ? b_ih_b : b_ih_f;
            const float* bi1 = dir ? b_hh_b : b_hh_f;
            float* Cg = dir ? gxT_b : gxT_f;
            const int m0 = mtile * 64, n0 = nt * 64;
            tile64_compute(hen_bf + (size_t)(m0 + r0) * 512 + c0,
                           Bw + (size_t)(n0 + r0) * 512 + c0, 512, smem, tid, acc);
#pragma unroll
            for (int i = 0; i < 2; ++i)
#pragma unroll
                for (int r = 0; r < 4; ++r) {
                    int m = m0 + wm + i * 16 + rq + r;
#pragma unroll
                    for (int j2 = 0; j2 < 2; ++j2) {
                        int n = n0 + wn + j2 * 16 + col;
                        st_f32_sc1(&Cg[(size_t)m * G4 + (n & 511) * 4 + (n >> 9)],
                                   acc[i][j2][r] + bi0[n] + bi1[n]);
                    }
                }
            asm volatile("s_waitcnt vmcnt(0)" ::: "memory");
            __syncthreads();
            if (tid == 0) atomicAdd(&gcnt[dir * 8 + mtile], 1);
            return;
        }
        if (bid < 1088) {
            // ---- conv -> x_em (sc1, read in-kernel by attention) ----
            const int cbid = bid - 576;
            const int n0 = (cbid & 7) * 64, m0 = (cbid >> 3) * 64;
            const int b = m0 >> 8, s0 = m0 & 255, y0 = s0 >> 5;
            const int y = y0 + (r0 >> 5), x = r0 & 31;
            const ushort* Abase = padT + (((size_t)b * PADH + y) * PADW + x) * CDIM + c0;
            const ushort* Bbase = Wt + (size_t)(n0 + r0) * CDIM + c0;
            for (int tap = 0; tap < 9; ++tap) {
                const int dy = tap / 3, dx = tap % 3;
                tile64_compute(Abase + ((size_t)dy * PADW + dx) * CDIM,
                               Bbase + (size_t)tap * EDIM * CDIM, 512, smem, tid, acc);
            }
#pragma unroll
            for (int i = 0; i < 2; ++i)
#pragma unroll
                for (int r = 0; r < 4; ++r) {
                    int m = m0 + wm + i * 16 + rq + r;
                    int s = m & 255;
#pragma unroll
                    for (int j2 = 0; j2 < 2; ++j2) {
                        int e = n0 + wn + j2 * 16 + col;
                        st_f32_sc1(&xem[((size_t)b * EDIM + e) * HW + s],
                                   acc[i][j2][r] + bias_em[e]);
                    }
                }
            asm volatile("s_waitcnt vmcnt(0)" ::: "memory");
            __syncthreads();
            if (tid == 0) atomicAdd(ccnt, 1);
            return;
        }
        {
            // ---- W_comb = W_hem @ W_dec (sc1) ----
            const int wb = bid - 1088;
            const int mt = wb >> 4, nt = wb & 15;
            const int m0 = mt * 64, n0 = nt * 64;
            tile64_compute(Whem_bf + (size_t)(m0 + r0) * 512 + c0,
                           WdecT_bf + (size_t)(n0 + r0) * 512 + c0, 512, smem, tid, acc);
#pragma unroll
            for (int i = 0; i < 2; ++i)
#pragma unroll
                for (int r = 0; r < 4; ++r) {
                    int m = m0 + wm + i * 16 + rq + r;
#pragma unroll
                    for (int j2 = 0; j2 < 2; ++j2) {
                        int n = n0 + wn + j2 * 16 + col;
                        st_u16_sc1(&Wcomb_bf[(size_t)m * 1024 + n], bfr(acc[i][j2][r]));
                    }
                }
            asm volatile("s_waitcnt vmcnt(0)" ::: "memory");
            __syncthreads();
            if (tid == 0) atomicAdd(wcnt, 1);
            return;
        }
    }

    if (bid < 1344) {
        // ---- decode / h_em: wait for per-tile LSTM completion ----
        const int isHem = (bid >= 1280);
        const int blk = isHem ? (bid - 1280) : (bid - 1216);
        const int mt = blk >> 3, nt = blk & 7;
        // hs rows m = t*16+b, t in [4mt, 4mt+4): fwd flag >= 4mt+4, bwd >= 32-4mt
        if (tid < 64) {
            const int target = (lane < 32) ? (4 * mt + 4) : (32 - 4 * mt);
            for (;;) {
                int v = ld_i32_sc1(&flags[lane]);
                if (__all(v >= target)) break;
                __builtin_amdgcn_s_sleep(8);
            }
            if (isHem && lane == 0)
                while (ld_i32_sc1(wcnt) < 128) __builtin_amdgcn_s_sleep(8);
        }
        __syncthreads();
        f32x4 acc[2][2];
#pragma unroll
        for (int i = 0; i < 2; ++i)
#pragma unroll
            for (int j = 0; j < 2; ++j) acc[i][j] = {0.f, 0.f, 0.f, 0.f};
        const int m0 = mt * 64, n0 = nt * 64;
        tile64_compute(hs_bf + (size_t)(m0 + r0) * 1024 + c0,
                       (isHem ? Wcomb_bf : Wdec_bf) + (size_t)(n0 + r0) * 1024 + c0,
                       1024, smem, tid, acc);
        if (!isHem) {
#pragma unroll
            for (int i = 0; i < 2; ++i)
#pragma unroll
                for (int r = 0; r < 4; ++r) {
                    int m = m0 + wm + i * 16 + rq + r;
                    int t = m >> 4, b = m & 15;
#pragma unroll
                    for (int j2 = 0; j2 < 2; ++j2) {
                        int n = n0 + wn + j2 * 16 + col;
                        out[((size_t)(b * T_LEN + t)) * 1024 + n] = acc[i][j2][r] + b_dec[n];
                    }
                }
        } else {
#pragma unroll
            for (int i = 0; i < 2; ++i)
#pragma unroll
                for (int r = 0; r < 4; ++r) {
                    int m = m0 + wm + i * 16 + rq + r;
#pragma unroll
                    for (int j2 = 0; j2 < 2; ++j2) {
                        int n = n0 + wn + j2 * 16 + col;
                        st_f32_sc1(&h_em[(size_t)m * 512 + n], acc[i][j2][r] + b_comb[n]);
                    }
                }
            asm volatile("s_waitcnt vmcnt(0)" ::: "memory");
            __syncthreads();
            if (tid == 0) atomicAdd(&hcnt[mt], 1);
        }
        return;
    }

    // ---- attention (waits hcnt tile + conv completion) ----
    {
        int i = bid - 1344;
        int k = i >> 3;
        int b = ((i & 7) << 1) | (k & 1);
        int t = k >> 1;
        int tb = t * 16 + b;
        const int mt = tb >> 6;
        if (tid == 0) {
            while (ld_i32_sc1(&hcnt[mt]) < 8) __builtin_amdgcn_s_sleep(8);
            while (ld_i32_sc1(ccnt) < 512) __builtin_amdgcn_s_sleep(8);
        }
        __syncthreads();
        float* fs = (float*)smem;
        float* hl = fs;
        float* wl = fs + 512;
        float* al = fs + 1024;
        float* red = fs + 1280;
        for (int q = tid; q < 512; q += 256) {
            hl[q] = ld_f32_sc1(&h_em[(size_t)tb * 512 + q]);
            wl[q] = watt[q];
        }
        __syncthreads();
        const float* xb = xem + (size_t)b * EDIM * HW;
        float sc = 0.f;
#pragma unroll 4
        for (int e = 0; e < 512; ++e)
            sc += ftanh(xb[(size_t)e * HW + tid] + hl[e]) * wl[e];
        float m = sc;
#pragma unroll
        for (int o = 32; o; o >>= 1) m = fmaxf(m, __shfl_xor(m, o));
        if ((tid & 63) == 0) red[tid >> 6] = m;
        __syncthreads();
        m = fmaxf(fmaxf(red[0], red[1]), fmaxf(red[2], red[3]));
        float ex = __expf(sc - m);
        float s = ex;
#pragma unroll
        for (int o = 32; o; o >>= 1) s += __shfl_xor(s, o);
        if ((tid & 63) == 0) red[4 + (tid >> 6)] = s;
        __syncthreads();
        s = red[4] + red[5] + red[6] + red[7];
        al[tid] = ex * frcp(s);
        __syncthreads();
        float* ob = out + ((size_t)(b * T_LEN + t)) * 1024 + 512;
        for (int eo = 0; eo < 512; eo += 256) {
            int e = eo + tid;
            const float* xr = xb + (size_t)e * HW;
            float acc2 = 0.f;
#pragma unroll 4
            for (int n = 0; n < 256; n += 4) {
                float4 v = *(const float4*)&xr[n];
                acc2 += al[n] * v.x + al[n + 1] * v.y + al[n + 2] * v.z + al[n + 3] * v.w;
            }
            ob[e] = acc2;
        }
    }
}

// ---------------------------------------------------------------------------
extern "C" void kernel_launch(void* const* d_in, const int* in_sizes, int n_in,
                              void* d_out, int out_size, void* d_ws, size_t ws_size,
                              hipStream_t stream) {
    const float* hidden_en = (const float*)d_in[0];
    const float* conv_f    = (const float*)d_in[1];
    const float* W_ih_f    = (const float*)d_in[2];
    const float* W_hh_f    = (const float*)d_in[3];
    const float* b_ih_f    = (const float*)d_in[4];
    const float* b_hh_f    = (const float*)d_in[5];
    const float* W_ih_b    = (const float*)d_in[6];
    const float* W_hh_b    = (const float*)d_in[7];
    const float* b_ih_b    = (const float*)d_in[8];
    const float* b_hh_b    = (const float*)d_in[9];
    const float* W_dec     = (const float*)d_in[10];
    const float* b_dec     = (const float*)d_in[11];
    const float* W_em      = (const float*)d_in[12];
    const float* b_em      = (const float*)d_in[13];
    const float* W_hem     = (const float*)d_in[14];
    const float* b_hem     = (const float*)d_in[15];
    const float* w_att     = (const float*)d_in[16];
    float* out = (float*)d_out;

    char* p = (char*)d_ws;
    auto alloc = [&](size_t bytes) { void* r = p; p += (bytes + 255) & ~(size_t)255; return r; };
    float*    gxT_f   = (float*)alloc((size_t)T_LEN * BATCH * G4 * 4);
    float*    gxT_b   = (float*)alloc((size_t)T_LEN * BATCH * G4 * 4);
    float*    h_em    = (float*)alloc((size_t)T_LEN * BATCH * 512 * 4);
    float*    x_em    = (float*)alloc((size_t)BATCH * EDIM * HW * 4);
    ushort*   padT    = (ushort*)alloc((size_t)BATCH * PADH * PADW * CDIM * 2);
    ushort*   Wt      = (ushort*)alloc((size_t)9 * EDIM * CDIM * 2);
    ushort*   hen_bf  = (ushort*)alloc((size_t)T_LEN * BATCH * DDIM * 2);
    ushort*   Wihf_bf = (ushort*)alloc((size_t)G4 * DDIM * 2);
    ushort*   Wihb_bf = (ushort*)alloc((size_t)G4 * DDIM * 2);
    ushort*   Whhf_bf = (ushort*)alloc((size_t)G4 * HDIM * 2);
    ushort*   Whhb_bf = (ushort*)alloc((size_t)G4 * HDIM * 2);
    ushort*   Wdec_bf = (ushort*)alloc((size_t)HDIM * 1024 * 2);
    ushort*   Whem_bf = (ushort*)alloc((size_t)EDIM * HDIM * 2);
    ushort*   WdecT_bf= (ushort*)alloc((size_t)1024 * 512 * 2);
    ushort*   Wcomb_bf= (ushort*)alloc((size_t)512 * 1024 * 2);
    float*    b_comb  = (float*)alloc(512 * 4);
    ushort*   hs_bf   = (ushort*)alloc((size_t)T_LEN * BATCH * 1024 * 2);
    int*      syncbuf = (int*)alloc(1024);

    PrepArgs pa;
    pa.s[0] = hidden_en; pa.d[0] = hen_bf;
    pa.s[1] = W_ih_f;    pa.d[1] = Wihf_bf;
    pa.s[2] = W_ih_b;    pa.d[2] = Wihb_bf;
    pa.s[3] = W_hh_f;    pa.d[3] = Whhf_bf;
    pa.s[4] = W_hh_b;    pa.d[4] = Whhb_bf;
    pa.s[5] = W_dec;     pa.d[5] = Wdec_bf;
    pa.s[6] = W_hem;     pa.d[6] = Whem_bf;
    prep_all<<<17570, 256, 0, stream>>>(pa, syncbuf, conv_f, padT, W_em, Wt,
                                        W_dec, WdecT_bf, W_hem, b_dec, b_hem, b_comb);

    // everything else: one persistent kernel
    fused_all<<<1856, 256, 0, stream>>>(Whhf_bf, Whhb_bf, gxT_f, gxT_b, hen_bf,
                                        Wihf_bf, Wihb_bf, b_ih_f, b_hh_f,
                                        b_ih_b, b_hh_b, hs_bf, syncbuf,
                                        padT, Wt, b_em, x_em,
                                        Whem_bf, WdecT_bf, Wcomb_bf,
                                        Wdec_bf, b_dec, b_comb, h_em,
                                        w_att, out);
}

// Round 13
// 263.505 us; speedup vs baseline: 1.2437x; 1.0666x over previous
//
#include <hip/hip_runtime.h>
#include <hip/hip_bf16.h>
#include <math.h>

// Dims (fixed by the problem)
#define T_LEN 32
#define BATCH 16
#define DDIM  512
#define HDIM  512
#define EDIM  512
#define CDIM  512
#define FHH   8
#define FWW   32
#define HW    256         // FHH*FWW
#define G4    2048        // 4*HDIM
#define PADH  10
#define PADW  34
#define WLP   520         // padded LDS row stride (ushorts)

typedef __attribute__((ext_vector_type(8))) short bf16x8;
typedef __attribute__((ext_vector_type(4))) float f32x4;
typedef __attribute__((ext_vector_type(4))) int i32x4;

// round-to-nearest-even f32 -> bf16 bits
__device__ __forceinline__ ushort bfr(float x) {
    union { float f; uint32_t u; } c; c.f = x;
    uint32_t r = (c.u + 0x7FFFu + ((c.u >> 16) & 1u)) >> 16;
    return (ushort)r;
}

__device__ __forceinline__ float frcp(float x) { return __builtin_amdgcn_rcpf(x); }
__device__ __forceinline__ float ftanh(float x) {
    return 1.f - 2.f * frcp(1.f + __expf(2.f * x));
}
__device__ __forceinline__ float fsig(float x) {
    return frcp(1.f + __expf(-x));
}

__device__ __forceinline__ void ld_lds16(const void* g, void* l) {
    __builtin_amdgcn_global_load_lds((const __attribute__((address_space(1))) void*)g,
                                     (__attribute__((address_space(3))) void*)l, 16, 0, 0);
}

// ---- sc1 = MALL-coherent (cross-XCD) accesses ----
__device__ __forceinline__ void st_u16_sc1(ushort* p, ushort v) {
    asm volatile("global_store_short %0, %1, off sc1" :: "v"(p), "v"((uint)v) : "memory");
}
__device__ __forceinline__ void st_i32_sc1(int* p, int v) {
    asm volatile("global_store_dword %0, %1, off sc1" :: "v"(p), "v"(v) : "memory");
}
__device__ __forceinline__ void st_f32_sc1(float* p, float v) {
    asm volatile("global_store_dword %0, %1, off sc1" :: "v"(p), "v"(v) : "memory");
}
__device__ __forceinline__ int ld_i32_sc1(const int* p) {
    int v;
    asm volatile("global_load_dword %0, %1, off sc1\n\ts_waitcnt vmcnt(0)"
                 : "=v"(v) : "v"(p) : "memory");
    return v;
}
__device__ __forceinline__ i32x4 ld_i32x4_sc1(const int* p) {
    i32x4 v;
    asm volatile("global_load_dwordx4 %0, %1, off sc1\n\ts_waitcnt vmcnt(0)"
                 : "=v"(v) : "v"(p) : "memory");
    return v;
}
__device__ __forceinline__ float ld_f32_sc1(const float* p) {
    float v;
    asm volatile("global_load_dword %0, %1, off sc1\n\ts_waitcnt vmcnt(0)"
                 : "=v"(v) : "v"(p) : "memory");
    return v;
}
// no waitcnt -- caller must vmcnt(0)+sched_barrier before use
__device__ __forceinline__ f32x4 ld_f32x4_sc1_async(const float* p) {
    f32x4 v;
    asm volatile("global_load_dwordx4 %0, %1, off sc1" : "=v"(v) : "v"(p));
    return v;
}

// ---------------------------------------------------------------------------
// prep_all: one launch for all preprocessing.
//   [0,5120):      f32->bf16 of 7 tensors + zero syncbuf[0..127] (sc1)
//   [5120,7168):   conv_f -> padT interior
//   [7168,7840):   padT border zeros
//   [7840,8352):   W_em -> Wt (9,E,C), COALESCED via per-e LDS transpose
//   [8352,8864):   W_dec -> WdecT bf16
//   [8864,8866):   b_comb[e] = W_hem[e,:]·b_dec + b_hem[e]
// ---------------------------------------------------------------------------
struct PrepArgs { const float* s[7]; ushort* d[7]; };
__global__ __launch_bounds__(256) void prep_all(
    PrepArgs a, int* __restrict__ syncbuf,
    const float* __restrict__ conv_f, ushort* __restrict__ padT,
    const float* __restrict__ W_em, ushort* __restrict__ Wt,
    const float* __restrict__ W_dec, ushort* __restrict__ WdecT,
    const float* __restrict__ W_hem, const float* __restrict__ b_dec,
    const float* __restrict__ b_hem, float* __restrict__ b_comb)
{
    __shared__ float tile[32][33];
    __shared__ ushort lt[9 * 512];
    const int bid = blockIdx.x, tid = threadIdx.x;
    if (bid < 5120) {
        int i = bid * 256 + tid;
        if (i < 128) st_i32_sc1(syncbuf + i, 0);
        const int e0 = 65536, e1 = 327680, e2 = 589824, e3 = 851968,
                  e4 = 1114112, e5 = 1245184;
        int seg, base;
        if      (i < e0) { seg = 0; base = 0;  }
        else if (i < e1) { seg = 1; base = e0; }
        else if (i < e2) { seg = 2; base = e1; }
        else if (i < e3) { seg = 3; base = e2; }
        else if (i < e4) { seg = 4; base = e3; }
        else if (i < e5) { seg = 5; base = e4; }
        else             { seg = 6; base = e5; }
        int li = i - base;
        float4 v = ((const float4*)a.s[seg])[li];
        ushort4 o;
        o.x = bfr(v.x); o.y = bfr(v.y); o.z = bfr(v.z); o.w = bfr(v.w);
        ((ushort4*)a.d[seg])[li] = o;
        return;
    }
    if (bid < 7168) {
        int id = bid - 5120;
        int s0 = (id & 7) * 32, c0 = ((id >> 3) & 15) * 32, b = id >> 7;
        int lo = tid & 31, hi = tid >> 5;
#pragma unroll
        for (int it = 0; it < 4; ++it) {
            int cl = hi + it * 8;
            tile[cl][lo] = conv_f[((size_t)(b * CDIM + c0 + cl)) * HW + s0 + lo];
        }
        __syncthreads();
#pragma unroll
        for (int it = 0; it < 4; ++it) {
            int sl = hi + it * 8;
            int s = s0 + sl;
            int y = s >> 5, x = s & 31;
            padT[(((size_t)b * PADH + y + 1) * PADW + (x + 1)) * CDIM + c0 + lo] =
                bfr(tile[lo][sl]);
        }
        return;
    }
    if (bid < 7840) {
        int gid = (bid - 7168) * 256 + tid;
        int c4 = gid & 127;
        int cellb = gid >> 7;
        int cell = cellb % 84;
        int b = cellb / 84;
        int y, x;
        if (cell < 34) { y = 0; x = cell; }
        else if (cell < 68) { y = 9; x = cell - 34; }
        else { int k2 = cell - 68; y = 1 + (k2 >> 1); x = (k2 & 1) ? 33 : 0; }
        ((ushort4*)padT)[(((size_t)b * PADH + y) * PADW + x) * (CDIM / 4) + c4] =
            make_ushort4(0, 0, 0, 0);
        return;
    }
    if (bid < 8352) {
        // ---- Wt repack, coalesced: block per e ----
        const int e = bid - 7840;
        const float4* src = (const float4*)(W_em + (size_t)e * 4608);
        for (int k = tid; k < 1152; k += 256) {
            float4 v = src[k];
            int base = k * 4;
#pragma unroll
            for (int j = 0; j < 4; ++j) {
                int idx = base + j;
                int c = idx / 9, tap = idx % 9;
                lt[tap * 512 + c] = bfr(((const float*)&v)[j]);
            }
        }
        __syncthreads();
        for (int k = tid; k < 1152; k += 256) {
            int tap = k >> 7, c4 = k & 127;
            ((ushort4*)(Wt + ((size_t)tap * EDIM + e) * CDIM))[c4] = ((ushort4*)lt)[k];
        }
        return;
    }
    if (bid < 8864) {
        int idx = bid - 8352;
        int ht = idx & 15, kt = idx >> 4;
        int h0 = ht * 32, k0 = kt * 32;
        int lo = tid & 31, hi = tid >> 5;
#pragma unroll
        for (int it = 0; it < 4; ++it) {
            int i = hi + it * 8;
            tile[i][lo] = W_dec[(size_t)(h0 + i) * 1024 + k0 + lo];
        }
        __syncthreads();
#pragma unroll
        for (int it = 0; it < 4; ++it) {
            int i = hi + it * 8;
            WdecT[(size_t)(k0 + i) * 512 + h0 + lo] = bfr(tile[lo][i]);
        }
        return;
    }
    {
        int e = (bid - 8864) * 256 + tid;
        float s = b_hem[e];
        const float* wr = W_hem + (size_t)e * 512;
        for (int h = 0; h < 512; ++h) s += wr[h] * b_dec[h];
        b_comb[e] = s;
    }
}

// ---------------------------------------------------------------------------
// shared 64x64 MFMA tile compute: acc += A_tile @ B_tile^T over K.
// ---------------------------------------------------------------------------
__device__ __forceinline__ void tile64_compute(
    const ushort* Ap0, const ushort* Bp0, int K,
    ushort* smem, int tid, f32x4 (&acc)[2][2])
{
    ushort* As = smem;
    ushort* Bs = smem + 2048;
    const int w = tid >> 6, lane = tid & 63;
    ushort* AsW = &As[w * 512];
    ushort* BsW = &Bs[w * 512];
    const int wm = (w >> 1) * 32, wn = (w & 1) * 32;
    const int kb = (lane >> 4) * 8, fr = lane & 15;
    for (int kk = 0; kk < K; kk += 32) {
        __syncthreads();
        ld_lds16(Ap0 + kk, AsW);
        ld_lds16(Bp0 + kk, BsW);
        __syncthreads();
        bf16x8 af[2], bg[2];
#pragma unroll
        for (int i = 0; i < 2; ++i)
            af[i] = *(const bf16x8*)&As[(wm + i * 16 + fr) * 32 + kb];
#pragma unroll
        for (int j = 0; j < 2; ++j)
            bg[j] = *(const bf16x8*)&Bs[(wn + j * 16 + fr) * 32 + kb];
#pragma unroll
        for (int i = 0; i < 2; ++i)
#pragma unroll
            for (int j = 0; j < 2; ++j)
                acc[i][j] = __builtin_amdgcn_mfma_f32_16x16x32_bf16(af[i], bg[j], acc[i][j], 0, 0, 0);
    }
}

// ---------------------------------------------------------------------------
// fused_main (R7-proven structure + W_comb tiles):
//   [0,64):      LSTM (sc1 flag exchange).
//   [64,576):    gx producers -> gxT (sc1) + gcnt.
//   [576,1088):  conv -> x_em (plain stores; consumed next kernel).
//   [1088,1216): W_comb = W_hem @ W_dec (plain stores; consumed next kernel).
// syncbuf: [0..63] flags, [64..79] gcnt (zeroed by prep, sc1).
// ---------------------------------------------------------------------------
__global__ __launch_bounds__(256) void fused_main(
    const ushort* __restrict__ Whh_f, const ushort* __restrict__ Whh_b,
    float* __restrict__ gxT_f, float* __restrict__ gxT_b,
    const ushort* __restrict__ hen_bf,
    const ushort* __restrict__ Wih_f, const ushort* __restrict__ Wih_b,
    const float* __restrict__ b_ih_f, const float* __restrict__ b_hh_f,
    const float* __restrict__ b_ih_b, const float* __restrict__ b_hh_b,
    ushort* __restrict__ hs_bf,
    int* __restrict__ syncbuf,
    const ushort* __restrict__ padT, const ushort* __restrict__ Wt,
    const float* __restrict__ bias_em, float* __restrict__ xem,
    const ushort* __restrict__ Whem_bf, const ushort* __restrict__ WdecT_bf,
    ushort* __restrict__ Wcomb_bf)
{
    __shared__ ushort smem[64 * WLP];
    const int bid = blockIdx.x, tid = threadIdx.x;
    const int w = tid >> 6, lane = tid & 63;
    int* flags = syncbuf;
    int* gcnt  = syncbuf + 64;

    if (bid < 64) {
        // ======================= LSTM =======================
        const int dir = bid >> 5;
        const int j0 = (bid & 31) * 16;
        const ushort* W = dir ? Whh_b : Whh_f;
        const float* gx = dir ? gxT_b : gxT_f;
#pragma unroll
        for (int i = 0; i < 16; ++i) {
            int row = w * 16 + i;
            int g = row >> 4, jl = row & 15;
            bf16x8 v = *(const bf16x8*)(W + ((size_t)(g * 512 + j0 + jl)) * 512 + lane * 8);
            *(bf16x8*)&smem[row * WLP + lane * 8] = v;
        }
        __syncthreads();
        if (tid >= 64) return;
        __builtin_amdgcn_s_setprio(1);

        const int fr = lane & 15, kq = lane >> 4;
        const int j = j0 + fr;
        const int* fq4 = &flags[dir * 32 + (lane & 7) * 4];
        const int t0 = dir ? (T_LEN - 1) : 0;
        int mt_ok = t0 >> 2;
        {
            const int* gp = &gcnt[dir * 8 + mt_ok];
            while (ld_i32_sc1(gp) < 32) __builtin_amdgcn_s_sleep(4);
        }
        f32x4 gq[4];
#pragma unroll
        for (int r = 0; r < 4; ++r)
            gq[r] = ld_f32x4_sc1_async(gx + (((size_t)t0 * BATCH + kq * 4 + r) * 512 + j) * 4);
        f32x4 cr = {0.f, 0.f, 0.f, 0.f};
        for (int step = 0; step < T_LEN; ++step) {
            const int tcur = dir ? (T_LEN - 1 - step) : step;
            if (step > 0) {
                const int need = step;
                for (;;) {
                    i32x4 v = ld_i32x4_sc1(fq4);
                    int mn = min(min(v[0], v[1]), min(v[2], v[3]));
                    if (__all(mn >= need)) break;
                    __builtin_amdgcn_s_sleep(1);
                }
            }
            f32x4 acc[4];
#pragma unroll
            for (int g = 0; g < 4; ++g) acc[g] = {0.f, 0.f, 0.f, 0.f};
            if (step > 0) {
                const int tprev = dir ? tcur + 1 : tcur - 1;
                const ushort* hp = hs_bf + ((size_t)tprev * BATCH + fr) * 1024 + dir * 512 + kq * 8;
                bf16x8 hreg[16];
#pragma unroll
                for (int u = 0; u < 16; ++u)
                    asm volatile("global_load_dwordx4 %0, %1, off sc1"
                                 : "=v"(hreg[u]) : "v"(hp + u * 32));
                asm volatile("s_waitcnt vmcnt(0)" ::: "memory");
                __builtin_amdgcn_sched_barrier(0);
#pragma unroll
                for (int u = 0; u < 16; ++u) {
#pragma unroll
                    for (int g = 0; g < 4; ++g) {
                        bf16x8 bb = *(const bf16x8*)&smem[(g * 16 + fr) * WLP + kq * 8 + u * 32];
                        acc[g] = __builtin_amdgcn_mfma_f32_16x16x32_bf16(hreg[u], bb, acc[g], 0, 0, 0);
                    }
                }
            } else {
                asm volatile("s_waitcnt vmcnt(0)" ::: "memory");  // gq arrival
                __builtin_amdgcn_sched_barrier(0);
            }
#pragma unroll
            for (int r = 0; r < 4; ++r) {
                int b = kq * 4 + r;
                float gi = gq[r][0] + acc[0][r];
                float gf = gq[r][1] + acc[1][r];
                float gg = gq[r][2] + acc[2][r];
                float go = gq[r][3] + acc[3][r];
                float si = fsig(gi), sf = fsig(gf), so = fsig(go);
                float c = sf * cr[r] + si * ftanh(gg);
                cr[r] = c;
                float h = so * ftanh(c);
                st_u16_sc1(hs_bf + ((size_t)tcur * BATCH + b) * 1024 + dir * 512 + j, bfr(h));
            }
            if (step < T_LEN - 1) {
                asm volatile("s_waitcnt vmcnt(0)" ::: "memory");   // h committed to MALL
                if (lane == 0) st_i32_sc1(&flags[bid], step + 1);
                const int tnext = dir ? tcur - 1 : tcur + 1;
                const int mtn = tnext >> 2;
                if (mtn != mt_ok) {
                    const int* gp = &gcnt[dir * 8 + mtn];
                    while (ld_i32_sc1(gp) < 32) __builtin_amdgcn_s_sleep(2);
                    mt_ok = mtn;
                }
#pragma unroll
                for (int r = 0; r < 4; ++r)
                    gq[r] = ld_f32x4_sc1_async(gx + (((size_t)tnext * BATCH + kq * 4 + r) * 512 + j) * 4);
            }
        }
        return;
    }

    const int r0 = tid >> 2, c0 = (tid & 3) * 8;
    const int wm = (w >> 1) * 32, wn = (w & 1) * 32;
    const int col = lane & 15, rq = (lane >> 4) * 4;
    f32x4 acc[2][2];
#pragma unroll
    for (int i = 0; i < 2; ++i)
#pragma unroll
        for (int j = 0; j < 2; ++j) acc[i][j] = {0.f, 0.f, 0.f, 0.f};

    if (bid < 576) {
        // ---- gx producers ----
        const int gi = bid - 64;
        const int dir = gi & 1;
        const int q = gi >> 1;
        const int nt = q & 31;
        const int mt0 = q >> 5;
        const int mtile = dir ? (7 - mt0) : mt0;
        const ushort* Bw = dir ? Wih_b : Wih_f;
        const float* bi0 = dir ? b_ih_b : b_ih_f;
        const float* bi1 = dir ? b_hh_b : b_hh_f;
        float* Cg = dir ? gxT_b : gxT_f;
        const int m0 = mtile * 64, n0 = nt * 64;
        tile64_compute(hen_bf + (size_t)(m0 + r0) * 512 + c0,
                       Bw + (size_t)(n0 + r0) * 512 + c0, 512, smem, tid, acc);
#pragma unroll
        for (int i = 0; i < 2; ++i)
#pragma unroll
            for (int r = 0; r < 4; ++r) {
                int m = m0 + wm + i * 16 + rq + r;
#pragma unroll
                for (int j2 = 0; j2 < 2; ++j2) {
                    int n = n0 + wn + j2 * 16 + col;
                    st_f32_sc1(&Cg[(size_t)m * G4 + (n & 511) * 4 + (n >> 9)],
                               acc[i][j2][r] + bi0[n] + bi1[n]);
                }
            }
        asm volatile("s_waitcnt vmcnt(0)" ::: "memory");
        __syncthreads();
        if (tid == 0) atomicAdd(&gcnt[dir * 8 + mtile], 1);
        return;
    }
    if (bid < 1088) {
        // ---- conv (plain stores; consumed by tail kernel) ----
        const int cbid = bid - 576;
        const int n0 = (cbid & 7) * 64, m0 = (cbid >> 3) * 64;
        const int b = m0 >> 8, s0 = m0 & 255, y0 = s0 >> 5;
        const int y = y0 + (r0 >> 5), x = r0 & 31;
        const ushort* Abase = padT + (((size_t)b * PADH + y) * PADW + x) * CDIM + c0;
        const ushort* Bbase = Wt + (size_t)(n0 + r0) * CDIM + c0;
        for (int tap = 0; tap < 9; ++tap) {
            const int dy = tap / 3, dx = tap % 3;
            tile64_compute(Abase + ((size_t)dy * PADW + dx) * CDIM,
                           Bbase + (size_t)tap * EDIM * CDIM, 512, smem, tid, acc);
        }
#pragma unroll
        for (int i = 0; i < 2; ++i)
#pragma unroll
            for (int r = 0; r < 4; ++r) {
                int m = m0 + wm + i * 16 + rq + r;
                int s = m & 255;
#pragma unroll
                for (int j2 = 0; j2 < 2; ++j2) {
                    int e = n0 + wn + j2 * 16 + col;
                    xem[((size_t)b * EDIM + e) * HW + s] = acc[i][j2][r] + bias_em[e];
                }
            }
        return;
    }
    {
        // ---- W_comb = W_hem @ W_dec (plain stores) ----
        const int wb = bid - 1088;
        const int mt = wb >> 4, nt = wb & 15;
        const int m0 = mt * 64, n0 = nt * 64;
        tile64_compute(Whem_bf + (size_t)(m0 + r0) * 512 + c0,
                       WdecT_bf + (size_t)(n0 + r0) * 512 + c0, 512, smem, tid, acc);
#pragma unroll
        for (int i = 0; i < 2; ++i)
#pragma unroll
            for (int r = 0; r < 4; ++r) {
                int m = m0 + wm + i * 16 + rq + r;
#pragma unroll
                for (int j2 = 0; j2 < 2; ++j2) {
                    int n = n0 + wn + j2 * 16 + col;
                    Wcomb_bf[(size_t)m * 1024 + n] = bfr(acc[i][j2][r]);
                }
            }
    }
}

// ---------------------------------------------------------------------------
// tail: h_em FIRST (64 blocks, sc1 + hcnt) || decode (64 blocks) ||
// attention (512 blocks, waits on hcnt per m-tile). All inputs complete at
// kernel entry (stream boundary), so only hcnt gating is intra-kernel.
// ---------------------------------------------------------------------------
__global__ __launch_bounds__(256) void tail(
    const ushort* __restrict__ hs_bf, const ushort* __restrict__ Wdec_bf,
    const float* __restrict__ b_dec, float* __restrict__ out,
    const ushort* __restrict__ Wcomb_bf, const float* __restrict__ b_comb,
    float* __restrict__ h_em,
    const float* __restrict__ xem, const float* __restrict__ watt,
    int* __restrict__ syncbuf)
{
    __shared__ ushort smem[4096];
    int* hcnt = syncbuf + 96;
    const int bid = blockIdx.x, tid = threadIdx.x;
    const int w = tid >> 6, lane = tid & 63;
    const int r0 = tid >> 2, c0 = (tid & 3) * 8;
    const int wm = (w >> 1) * 32, wn = (w & 1) * 32;
    const int col = lane & 15, rq = (lane >> 4) * 4;

    if (bid < 128) {
        f32x4 acc[2][2];
#pragma unroll
        for (int i = 0; i < 2; ++i)
#pragma unroll
            for (int j = 0; j < 2; ++j) acc[i][j] = {0.f, 0.f, 0.f, 0.f};
        if (bid < 64) {
            // ---- h_em = hs @ W_comb^T + b_comb (sc1 + hcnt flag) ----
            const int mt = bid >> 3, nt = bid & 7;
            const int m0 = mt * 64, n0 = nt * 64;
            tile64_compute(hs_bf + (size_t)(m0 + r0) * 1024 + c0,
                           Wcomb_bf + (size_t)(n0 + r0) * 1024 + c0, 1024, smem, tid, acc);
#pragma unroll
            for (int i = 0; i < 2; ++i)
#pragma unroll
                for (int r = 0; r < 4; ++r) {
                    int m = m0 + wm + i * 16 + rq + r;
#pragma unroll
                    for (int j2 = 0; j2 < 2; ++j2) {
                        int n = n0 + wn + j2 * 16 + col;
                        st_f32_sc1(&h_em[(size_t)m * 512 + n], acc[i][j2][r] + b_comb[n]);
                    }
                }
            asm volatile("s_waitcnt vmcnt(0)" ::: "memory");
            __syncthreads();
            if (tid == 0) atomicAdd(&hcnt[mt], 1);
        } else {
            // ---- decode -> out[:, :, 0:512] ----
            const int blk = bid - 64;
            const int mt = blk >> 3, nt = blk & 7;
            const int m0 = mt * 64, n0 = nt * 64;
            tile64_compute(hs_bf + (size_t)(m0 + r0) * 1024 + c0,
                           Wdec_bf + (size_t)(n0 + r0) * 1024 + c0, 1024, smem, tid, acc);
#pragma unroll
            for (int i = 0; i < 2; ++i)
#pragma unroll
                for (int r = 0; r < 4; ++r) {
                    int m = m0 + wm + i * 16 + rq + r;
                    int t = m >> 4, b = m & 15;
#pragma unroll
                    for (int j2 = 0; j2 < 2; ++j2) {
                        int n = n0 + wn + j2 * 16 + col;
                        out[((size_t)(b * T_LEN + t)) * 1024 + n] = acc[i][j2][r] + b_dec[n];
                    }
                }
        }
        return;
    }

    // ---- attention ----
    {
        int i = bid - 128;
        int k = i >> 3;
        int b = ((i & 7) << 1) | (k & 1);
        int t = k >> 1;
        int tb = t * 16 + b;
        const int mt = tb >> 6;
        if (tid == 0) {
            while (ld_i32_sc1(&hcnt[mt]) < 8) __builtin_amdgcn_s_sleep(8);
        }
        __syncthreads();
        float* fs = (float*)smem;
        float* hl = fs;
        float* wl = fs + 512;
        float* al = fs + 1024;
        float* red = fs + 1280;
        for (int q = tid; q < 512; q += 256) {
            hl[q] = ld_f32_sc1(&h_em[(size_t)tb * 512 + q]);
            wl[q] = watt[q];
        }
        __syncthreads();
        const float* xb = xem + (size_t)b * EDIM * HW;
        float sc = 0.f;
#pragma unroll 4
        for (int e = 0; e < 512; ++e)
            sc += ftanh(xb[(size_t)e * HW + tid] + hl[e]) * wl[e];
        float m = sc;
#pragma unroll
        for (int o = 32; o; o >>= 1) m = fmaxf(m, __shfl_xor(m, o));
        if ((tid & 63) == 0) red[tid >> 6] = m;
        __syncthreads();
        m = fmaxf(fmaxf(red[0], red[1]), fmaxf(red[2], red[3]));
        float ex = __expf(sc - m);
        float s = ex;
#pragma unroll
        for (int o = 32; o; o >>= 1) s += __shfl_xor(s, o);
        if ((tid & 63) == 0) red[4 + (tid >> 6)] = s;
        __syncthreads();
        s = red[4] + red[5] + red[6] + red[7];
        al[tid] = ex * frcp(s);
        __syncthreads();
        float* ob = out + ((size_t)(b * T_LEN + t)) * 1024 + 512;
        for (int eo = 0; eo < 512; eo += 256) {
            int e = eo + tid;
            const float* xr = xb + (size_t)e * HW;
            float acc2 = 0.f;
#pragma unroll 4
            for (int n = 0; n < 256; n += 4) {
                float4 v = *(const float4*)&xr[n];
                acc2 += al[n] * v.x + al[n + 1] * v.y + al[n + 2] * v.z + al[n + 3] * v.w;
            }
            ob[e] = acc2;
        }
    }
}

// ---------------------------------------------------------------------------
extern "C" void kernel_launch(void* const* d_in, const int* in_sizes, int n_in,
                              void* d_out, int out_size, void* d_ws, size_t ws_size,
                              hipStream_t stream) {
    const float* hidden_en = (const float*)d_in[0];
    const float* conv_f    = (const float*)d_in[1];
    const float* W_ih_f    = (const float*)d_in[2];
    const float* W_hh_f    = (const float*)d_in[3];
    const float* b_ih_f    = (const float*)d_in[4];
    const float* b_hh_f    = (const float*)d_in[5];
    const float* W_ih_b    = (const float*)d_in[6];
    const float* W_hh_b    = (const float*)d_in[7];
    const float* b_ih_b    = (const float*)d_in[8];
    const float* b_hh_b    = (const float*)d_in[9];
    const float* W_dec     = (const float*)d_in[10];
    const float* b_dec     = (const float*)d_in[11];
    const float* W_em      = (const float*)d_in[12];
    const float* b_em      = (const float*)d_in[13];
    const float* W_hem     = (const float*)d_in[14];
    const float* b_hem     = (const float*)d_in[15];
    const float* w_att     = (const float*)d_in[16];
    float* out = (float*)d_out;

    char* p = (char*)d_ws;
    auto alloc = [&](size_t bytes) { void* r = p; p += (bytes + 255) & ~(size_t)255; return r; };
    float*    gxT_f   = (float*)alloc((size_t)T_LEN * BATCH * G4 * 4);
    float*    gxT_b   = (float*)alloc((size_t)T_LEN * BATCH * G4 * 4);
    float*    h_em    = (float*)alloc((size_t)T_LEN * BATCH * 512 * 4);
    float*    x_em    = (float*)alloc((size_t)BATCH * EDIM * HW * 4);
    ushort*   padT    = (ushort*)alloc((size_t)BATCH * PADH * PADW * CDIM * 2);
    ushort*   Wt      = (ushort*)alloc((size_t)9 * EDIM * CDIM * 2);
    ushort*   hen_bf  = (ushort*)alloc((size_t)T_LEN * BATCH * DDIM * 2);
    ushort*   Wihf_bf = (ushort*)alloc((size_t)G4 * DDIM * 2);
    ushort*   Wihb_bf = (ushort*)alloc((size_t)G4 * DDIM * 2);
    ushort*   Whhf_bf = (ushort*)alloc((size_t)G4 * HDIM * 2);
    ushort*   Whhb_bf = (ushort*)alloc((size_t)G4 * HDIM * 2);
    ushort*   Wdec_bf = (ushort*)alloc((size_t)HDIM * 1024 * 2);
    ushort*   Whem_bf = (ushort*)alloc((size_t)EDIM * HDIM * 2);
    ushort*   WdecT_bf= (ushort*)alloc((size_t)1024 * 512 * 2);
    ushort*   Wcomb_bf= (ushort*)alloc((size_t)512 * 1024 * 2);
    float*    b_comb  = (float*)alloc(512 * 4);
    ushort*   hs_bf   = (ushort*)alloc((size_t)T_LEN * BATCH * 1024 * 2);
    int*      syncbuf = (int*)alloc(1024);

    PrepArgs pa;
    pa.s[0] = hidden_en; pa.d[0] = hen_bf;
    pa.s[1] = W_ih_f;    pa.d[1] = Wihf_bf;
    pa.s[2] = W_ih_b;    pa.d[2] = Wihb_bf;
    pa.s[3] = W_hh_f;    pa.d[3] = Whhf_bf;
    pa.s[4] = W_hh_b;    pa.d[4] = Whhb_bf;
    pa.s[5] = W_dec;     pa.d[5] = Wdec_bf;
    pa.s[6] = W_hem;     pa.d[6] = Whem_bf;
    prep_all<<<8866, 256, 0, stream>>>(pa, syncbuf, conv_f, padT, W_em, Wt,
                                       W_dec, WdecT_bf, W_hem, b_dec, b_hem, b_comb);

    // LSTM + gx + conv + W_comb, one persistent launch (proven R7 structure)
    fused_main<<<1216, 256, 0, stream>>>(Whhf_bf, Whhb_bf, gxT_f, gxT_b, hen_bf,
                                         Wihf_bf, Wihb_bf, b_ih_f, b_hh_f,
                                         b_ih_b, b_hh_b, hs_bf, syncbuf,
                                         padT, Wt, b_em, x_em,
                                         Whem_bf, WdecT_bf, Wcomb_bf);

    // h_em || decode || attention
    tail<<<640, 256, 0, stream>>>(hs_bf, Wdec_bf, b_dec, out,
                                  Wcomb_bf, b_comb, h_em, x_em, w_att, syncbuf);
}